// Round 15
// baseline (1865.022 us; speedup 1.0000x reference)
//
#include <hip/hip_runtime.h>

// GINEEncoderBlock — round 17: lgkmcnt-only barriers in the edge GEMM K-loop.
// R16 null (3-deep === 2-deep) isolated the true stall: __syncthreads()
// lowers to s_waitcnt vmcnt(0) lgkmcnt(0) + s_barrier, force-draining every
// A-load at its issuing step's barrier -> prefetch coverage capped at ~1
// step (~470cyc) < es HBM latency (~900cyc), depth-independent. Our staging
// is REGISTER-staged (not global_load_lds): barrier correctness needs only
// lgkmcnt(0) (ds_writes visible cross-wave); vmcnt waits happen at register
// consumption automatically (in-order). So: raw s_barrier + lgkmcnt(0)
// lets A-loads live 2 full steps (issue@kc -> consume@kc+2 staging) >= HBM
// latency. 3-deep prefetch retained (now effective). Hazards: write(b^1)@kc
// -> lgkm(0)+bar -> read(b^1)@kc+1; read(cur)@kc drained by same lgkm(0)
// before write(cur)@kc+1. Epilogue keeps full __syncthreads (Tr aliasing).
// Everything else identical to the proven R15/R16 structure.

#define D 256
#define BN_EPS 1e-5f

typedef __attribute__((ext_vector_type(8))) short bf16x8;
typedef __attribute__((ext_vector_type(8))) ushort u16x8;
typedef __attribute__((ext_vector_type(4))) float f32x4;

__device__ __forceinline__ ushort bf16h(float f) {
    uint u = __float_as_uint(f);
    return (ushort)((u + 0x7FFFu + ((u >> 16) & 1u)) >> 16);
}
__device__ __forceinline__ float bf16f(ushort h) {
    return __uint_as_float(((uint)h) << 16);
}

// truncation split: h = top16(f), l = top16(f - h); h+l ~ f to ~2^-16 rel.
__device__ __forceinline__ void split2(float f, ushort& h, ushort& l) {
    uint u = __float_as_uint(f);
    h = (ushort)(u >> 16);
    float r = f - __uint_as_float(u & 0xFFFF0000u);
    l = (ushort)(__float_as_uint(r) >> 16);
}

__device__ __forceinline__ void cvt_write8(const float4& x0, const float4& x1,
                                           ushort* dh, ushort* dl) {
    float f[8] = {x0.x, x0.y, x0.z, x0.w, x1.x, x1.y, x1.z, x1.w};
    u16x8 hv, lv;
#pragma unroll
    for (int j = 0; j < 8; ++j) {
        ushort h, l;
        split2(f[j], h, l);
        hv[j] = h; lv[j] = l;
    }
    *(u16x8*)dh = hv;
    *(u16x8*)dl = lv;
}

// LDS-only barrier: drain own ds ops (cross-wave visibility), leave global
// loads in flight (they land in registers; consumption-point vmcnt waits
// are inserted by the compiler, in-order).
__device__ __forceinline__ void barrier_lds() {
    asm volatile("s_waitcnt lgkmcnt(0)" ::: "memory");
    __builtin_amdgcn_s_barrier();
}

// ------------------------------------------------------------- CSR build ----
__global__ __launch_bounds__(256) void hist_kernel(
    const int* __restrict__ dst, int* __restrict__ cnt, int E)
{
    int i = blockIdx.x * 256 + threadIdx.x;
    if (i < E) atomicAdd(&cnt[dst[i]], 1);
}

__global__ __launch_bounds__(256) void scan_kernel(
    const int* __restrict__ cnt, int* __restrict__ row_ptr, int N)
{
    __shared__ int buf[256];
    __shared__ int carry_s;
    if (threadIdx.x == 0) { carry_s = 0; row_ptr[0] = 0; }
    __syncthreads();
    for (int base = 0; base < N; base += 256) {
        int i = base + threadIdx.x;
        int v = (i < N) ? cnt[i] : 0;
        buf[threadIdx.x] = v;
        __syncthreads();
#pragma unroll
        for (int off = 1; off < 256; off <<= 1) {
            int t = (threadIdx.x >= off) ? buf[threadIdx.x - off] : 0;
            __syncthreads();
            buf[threadIdx.x] += t;
            __syncthreads();
        }
        int inc = buf[threadIdx.x] + carry_s;
        if (i < N) row_ptr[i + 1] = inc;
        __syncthreads();
        if (threadIdx.x == 255) carry_s = inc;
        __syncthreads();
    }
}

__global__ __launch_bounds__(256) void fill_kernel(
    const int* __restrict__ dst, const int* __restrict__ src,
    const int* __restrict__ row_ptr, int* __restrict__ fillc,
    int* __restrict__ edge_idx, int* __restrict__ src_sorted, int E)
{
    int i = blockIdx.x * 256 + threadIdx.x;
    if (i < E) {
        int d = dst[i];
        int pos = atomicAdd(&fillc[d], 1);
        int slot = row_ptr[d] + pos;
        edge_idx[slot] = i;
        src_sorted[slot] = src[i];
    }
}

// ------------------------------------------------------- gather (layer 0) ----
__global__ __launch_bounds__(256) void gather_l0(
    const float* __restrict__ x, const float* __restrict__ e32,
    const int* __restrict__ src, const int* __restrict__ row_ptr,
    const int* __restrict__ edge_idx, float* __restrict__ aggr, int N)
{
    int node = blockIdx.x * 4 + (threadIdx.x >> 6);
    if (node >= N) return;
    int lane = threadIdx.x & 63;
    int beg = row_ptr[node], end = row_ptr[node + 1];
    float4 acc = make_float4(0.f, 0.f, 0.f, 0.f);
    if (beg < end) {
        int ed0 = edge_idx[beg];
        int s0  = src[ed0];
        float4 e0 = ((const float4*)(e32 + (size_t)ed0 * D))[lane];
        float4 x0 = ((const float4*)(x + (size_t)s0 * D))[lane];
        for (int j = beg + 1; j < end; ++j) {
            int ed1 = edge_idx[j];
            int s1  = src[ed1];
            float4 e1 = ((const float4*)(e32 + (size_t)ed1 * D))[lane];
            float4 x1 = ((const float4*)(x + (size_t)s1 * D))[lane];
            acc.x += fmaxf(e0.x + x0.x, 0.f);
            acc.y += fmaxf(e0.y + x0.y, 0.f);
            acc.z += fmaxf(e0.z + x0.z, 0.f);
            acc.w += fmaxf(e0.w + x0.w, 0.f);
            e0 = e1; x0 = x1;
        }
        acc.x += fmaxf(e0.x + x0.x, 0.f);
        acc.y += fmaxf(e0.y + x0.y, 0.f);
        acc.z += fmaxf(e0.z + x0.z, 0.f);
        acc.w += fmaxf(e0.w + x0.w, 0.f);
    }
    ((float4*)(aggr + (size_t)node * D))[lane] = acc;
}

// ------------------------------------------------- gather (sorted, BN-x) ----
__global__ __launch_bounds__(256) void gather_sorted(
    const float* __restrict__ x, const ushort* __restrict__ es,
    const int* __restrict__ src_sorted, const int* __restrict__ row_ptr,
    const float* __restrict__ stats, const float* __restrict__ gamma,
    const float* __restrict__ beta, float* __restrict__ aggr, int N)
{
    __shared__ float ssc[256], ssf[256];
    {
        int c = threadIdx.x;
        float inv_n = 1.f / (float)N;
        float mean = stats[c] * inv_n;
        float var  = stats[D + c] * inv_n - mean * mean;
        float sc = gamma[c] * rsqrtf(var + BN_EPS);
        ssc[c] = sc;
        ssf[c] = beta[c] - mean * sc;
    }
    __syncthreads();
    int node = blockIdx.x * 4 + (threadIdx.x >> 6);
    if (node >= N) return;
    int lane = threadIdx.x & 63;
    float4 sc4 = *(const float4*)&ssc[lane * 4];
    float4 sh4 = *(const float4*)&ssf[lane * 4];
    int beg = row_ptr[node], end = row_ptr[node + 1];
    float4 acc = make_float4(0.f, 0.f, 0.f, 0.f);
    if (beg < end) {
        int s0 = src_sorted[beg];
        const ushort* er0 = es + (size_t)beg * 512;
        ushort4 hv0 = *(const ushort4*)(er0 + lane * 4);
        ushort4 lv0 = *(const ushort4*)(er0 + 256 + lane * 4);
        float4  xv0 = ((const float4*)(x + (size_t)s0 * D))[lane];
        for (int j = beg + 1; j < end; ++j) {
            int s1 = src_sorted[j];
            const ushort* er1 = es + (size_t)j * 512;
            ushort4 hv1 = *(const ushort4*)(er1 + lane * 4);
            ushort4 lv1 = *(const ushort4*)(er1 + 256 + lane * 4);
            float4  xv1 = ((const float4*)(x + (size_t)s1 * D))[lane];
            float4 ev;
            ev.x = bf16f(hv0.x) + bf16f(lv0.x);
            ev.y = bf16f(hv0.y) + bf16f(lv0.y);
            ev.z = bf16f(hv0.z) + bf16f(lv0.z);
            ev.w = bf16f(hv0.w) + bf16f(lv0.w);
            acc.x += fmaxf(xv0.x * sc4.x + sh4.x + ev.x, 0.f);
            acc.y += fmaxf(xv0.y * sc4.y + sh4.y + ev.y, 0.f);
            acc.z += fmaxf(xv0.z * sc4.z + sh4.z + ev.z, 0.f);
            acc.w += fmaxf(xv0.w * sc4.w + sh4.w + ev.w, 0.f);
            hv0 = hv1; lv0 = lv1; xv0 = xv1;
        }
        float4 ev;
        ev.x = bf16f(hv0.x) + bf16f(lv0.x);
        ev.y = bf16f(hv0.y) + bf16f(lv0.y);
        ev.z = bf16f(hv0.z) + bf16f(lv0.z);
        ev.w = bf16f(hv0.w) + bf16f(lv0.w);
        acc.x += fmaxf(xv0.x * sc4.x + sh4.x + ev.x, 0.f);
        acc.y += fmaxf(xv0.y * sc4.y + sh4.y + ev.y, 0.f);
        acc.z += fmaxf(xv0.z * sc4.z + sh4.z + ev.z, 0.f);
        acc.w += fmaxf(xv0.w * sc4.w + sh4.w + ev.w, 0.f);
    }
    ((float4*)(aggr + (size_t)node * D))[lane] = acc;
}

// ------------------------------------------- W -> K-chunk-major bf16 hi/lo --
__global__ __launch_bounds__(256) void wconv_kernel(
    const float* __restrict__ W, ushort* __restrict__ WTh,
    ushort* __restrict__ WTl)
{
    int bk = blockIdx.x;            // layer*D + k
    int col = threadIdx.x;
    int layer = bk >> 8, k = bk & 255;
    float v = W[(size_t)bk * D + col];
    ushort h = bf16h(v);
    ushort lo = bf16h(v - bf16f(h));
    size_t o = (((size_t)layer * 8 + (k >> 5)) * 256 + col) * 32 + (k & 31);
    WTh[o] = h;
    WTl[o] = lo;
}

// ----------------------------------------------------- MFMA edge GEMM -------
// R16 structure (3-deep A sets mod 3, W 1-deep) with lgkmcnt-only barriers
// in the K-loop. 64x256/block, 4 waves, 4x4 16x16x32 frags, hi/lo 3-MFMA;
// MODE 0 = permuted fp32 input (cvt staging), MODE 1 = es linear in-place.
// LDS union 34.8KB; epilogue Tr transpose -> es rows [256 hi][256 lo].
template<int MODE>
__global__ __launch_bounds__(256) void gemm_edge_mfma(
    const float* __restrict__ e32, const int* __restrict__ edge_idx,
    const ushort* __restrict__ esin, const ushort* __restrict__ WTh,
    const ushort* __restrict__ WTl, const float* __restrict__ bias,
    ushort* __restrict__ es, int rows)
{
    __shared__ char smem[34816];
    ushort* AhB = (ushort*)smem;              // [2][64][40]
    ushort* AlB = (ushort*)(smem + 10240);    // [2][64][40]
    float*  TrB = (float*)smem;               // [4][32][68] (epilogue reuse)
#define AH(b, r, c) AhB[(b) * 2560 + (r) * 40 + (c)]
#define AL(b, r, c) AlB[(b) * 2560 + (r) * 40 + (c)]
#define TR(w, r, c) TrB[(w) * 2176 + (r) * 68 + (c)]

    const int tid  = threadIdx.x;
    const int lane = tid & 63;
    const int wave = tid >> 6;
    const int m0   = blockIdx.x * 64;
    const int l15  = lane & 15;
    const int l4   = lane >> 4;
    const int wcol = wave * 64;

    const int srow = tid >> 2;    // 0..63
    const int ssec = tid & 3;     // 8-elem sector
    const int sgr  = m0 + srow;
    const bool svalid = (sgr < rows);

    f32x4 acc[4][4];
#pragma unroll
    for (int m = 0; m < 4; ++m)
#pragma unroll
        for (int n = 0; n < 4; ++n) acc[m][n] = (f32x4){0.f, 0.f, 0.f, 0.f};

    float4 pf0[3] = {}, pf1[3] = {};      // MODE0 prefetch sets (3-deep)
    u16x8  ph[3] = {}, pl[3] = {};        // MODE1 prefetch sets (3-deep)
    bf16x8 bh[4], bl[4], bhn[4], bln[4];

    const float*  a32 = nullptr;
    const ushort* ahi = nullptr;
    if (MODE == 0) {
        int erow = svalid ? edge_idx[sgr] : 0;
        a32 = e32 + (size_t)erow * D + ssec * 8;
    } else {
        ahi = esin + (size_t)sgr * 512 + ssec * 8;   // lo at +256
    }

    // ---- prologue: A chunks 0,1,2 -> sets 0,1,2; W chunk 0 -> regs ----
    if (svalid) {
#pragma unroll
        for (int c = 0; c < 3; ++c) {
            if (MODE == 0) {
                const float* p = a32 + c * 32;
                pf0[c] = *(const float4*)p;
                pf1[c] = *(const float4*)(p + 4);
            } else {
                ph[c] = *(const u16x8*)(ahi + c * 32);
                pl[c] = *(const u16x8*)(ahi + 256 + c * 32);
            }
        }
    }
#pragma unroll
    for (int n = 0; n < 4; ++n) {
        size_t o = ((size_t)(wcol + n * 16 + l15)) * 32 + l4 * 8;
        bh[n] = *(const bf16x8*)(WTh + o);
        bl[n] = *(const bf16x8*)(WTl + o);
    }
    if (MODE == 0) {
        cvt_write8(pf0[0], pf1[0], &AH(0, srow, ssec * 8), &AL(0, srow, ssec * 8));
    } else {
        *(u16x8*)&AH(0, srow, ssec * 8) = ph[0];
        *(u16x8*)&AL(0, srow, ssec * 8) = pl[0];
    }
    barrier_lds();   // sets 1,2 stay in flight across the barrier

    // ---- K loop: 8 chunks of 32; A 3-deep, W 1-deep prefetch ----
    // set s holds chunk === s (mod 3); chunk kc+3 (issued @kc) is consumed
    // by staging at step kc+2 -> ~2 full MFMA phases in flight, and the
    // lgkmcnt-only barrier no longer force-drains it.
#pragma unroll
    for (int kc = 0; kc < 8; ++kc) {
        const int cur = kc & 1;
        if (kc < 5 && svalid) {            // issue A(kc+3) into set kc%3
            if (MODE == 0) {
                const float* p = a32 + (kc + 3) * 32;
                pf0[kc % 3] = *(const float4*)p;
                pf1[kc % 3] = *(const float4*)(p + 4);
            } else {
                ph[kc % 3] = *(const u16x8*)(ahi + (kc + 3) * 32);
                pl[kc % 3] = *(const u16x8*)(ahi + 256 + (kc + 3) * 32);
            }
        }
        bf16x8 ah[4], al[4];
#pragma unroll
        for (int m = 0; m < 4; ++m) {
            ah[m] = *(const bf16x8*)&AH(cur, m * 16 + l15, l4 * 8);
            al[m] = *(const bf16x8*)&AL(cur, m * 16 + l15, l4 * 8);
        }
        if (kc < 7) {                      // issue W(kc+1)
#pragma unroll
            for (int n = 0; n < 4; ++n) {
                size_t o = ((size_t)(kc + 1) * 256 + wcol + n * 16 + l15) * 32 + l4 * 8;
                bhn[n] = *(const bf16x8*)(WTh + o);
                bln[n] = *(const bf16x8*)(WTl + o);
            }
        }
#pragma unroll
        for (int m = 0; m < 4; ++m)
#pragma unroll
            for (int n = 0; n < 4; ++n) {
                acc[m][n] = __builtin_amdgcn_mfma_f32_16x16x32_bf16(
                    ah[m], bh[n], acc[m][n], 0, 0, 0);
                acc[m][n] = __builtin_amdgcn_mfma_f32_16x16x32_bf16(
                    ah[m], bl[n], acc[m][n], 0, 0, 0);
                acc[m][n] = __builtin_amdgcn_mfma_f32_16x16x32_bf16(
                    al[m], bh[n], acc[m][n], 0, 0, 0);
            }
        if (kc < 7) {                      // stage A(kc+1) from set (kc+1)%3
            const int ns = (kc + 1) % 3;
            if (MODE == 0) {
                cvt_write8(pf0[ns], pf1[ns],
                           &AH(cur ^ 1, srow, ssec * 8), &AL(cur ^ 1, srow, ssec * 8));
            } else {
                *(u16x8*)&AH(cur ^ 1, srow, ssec * 8) = ph[ns];
                *(u16x8*)&AL(cur ^ 1, srow, ssec * 8) = pl[ns];
            }
#pragma unroll
            for (int n = 0; n < 4; ++n) { bh[n] = bhn[n]; bl[n] = bln[n]; }
        }
        barrier_lds();
    }

    // ---- epilogue: bias+relu -> LDS transpose -> es row stores ----
    // (full __syncthreads here: Tr aliases the A buffers; all loads are
    // already consumed by now, so the vmcnt drain is free)
#pragma unroll
    for (int h = 0; h < 2; ++h) {
        __syncthreads();
#pragma unroll
        for (int mm = 0; mm < 2; ++mm) {
            int m = h * 2 + mm;
#pragma unroll
            for (int n = 0; n < 4; ++n) {
                float bv = bias[wcol + n * 16 + l15];
#pragma unroll
                for (int r = 0; r < 4; ++r)
                    TR(wave, mm * 16 + l4 * 4 + r, n * 16 + l15) =
                        fmaxf(acc[m][n][r] + bv, 0.f);
            }
        }
        __syncthreads();
#pragma unroll
        for (int p = 0; p < 8; ++p) {
            int row  = p * 4 + l4;
            int grow = m0 + h * 32 + row;
            if (grow < rows) {
                float4 v = *(const float4*)&TR(wave, row, l15 * 4);
                ushort4 h4, l4v;
                split2(v.x, h4.x, l4v.x);
                split2(v.y, h4.y, l4v.y);
                split2(v.z, h4.z, l4v.z);
                split2(v.w, h4.w, l4v.w);
                size_t off = (size_t)grow * 512 + wcol + l15 * 4;
                *(ushort4*)(es + off) = h4;
                *(ushort4*)(es + off + 256) = l4v;
            }
        }
    }
#undef AH
#undef AL
#undef TR
}

// ------------------------------------------------------------------- GEMM ----
// fp32 row-full GEMM for node convs (N=10k). BN_A: scale/shift inline in
// LDS from stats_in+gamma/beta. DO_STATS: column sum/sumsq into stats_out.
template<bool BN_A, bool ADD_INIT, bool DO_STATS>
__global__ __launch_bounds__(256) void gemm_rowfull(
    const float* A, const float* __restrict__ aggr,
    const float* __restrict__ W, const float* __restrict__ bias,
    const float* __restrict__ stats_in, const float* __restrict__ gamma,
    const float* __restrict__ beta, const float* __restrict__ init,
    float* out, float* __restrict__ stats_out, int rows)
{
    __shared__ float As[16][68];
    __shared__ float Bs[16][260];
    __shared__ float ssc[256], ssf[256];

    const int tid = threadIdx.x;
    const int m0 = blockIdx.x * 64;
    const int tx = tid & 15;
    const int ty = tid >> 4;

    const int arow = tid >> 2;
    const int ak4  = (tid & 3) << 2;
    const int bk   = tid >> 4;
    const int bn4  = (tid & 15) << 2;

    if (BN_A) {
        float inv_n = 1.f / (float)rows;
        float mean = stats_in[tid] * inv_n;
        float var  = stats_in[D + tid] * inv_n - mean * mean;
        float sc = gamma[tid] * rsqrtf(var + BN_EPS);
        ssc[tid] = sc;
        ssf[tid] = beta[tid] - mean * sc;
        __syncthreads();
    }

    float acc[4][16];
#pragma unroll
    for (int i = 0; i < 4; ++i)
#pragma unroll
        for (int j = 0; j < 16; ++j) acc[i][j] = 0.f;

    for (int k0 = 0; k0 < D; k0 += 16) {
        float4 av = make_float4(0.f, 0.f, 0.f, 0.f);
        int gr = m0 + arow;
        if (gr < rows) {
            av = *(const float4*)(A + (size_t)gr * D + k0 + ak4);
            if (BN_A) {
                float4 sc = *(const float4*)&ssc[k0 + ak4];
                float4 sh = *(const float4*)&ssf[k0 + ak4];
                av.x = av.x * sc.x + sh.x;
                av.y = av.y * sc.y + sh.y;
                av.z = av.z * sc.z + sh.z;
                av.w = av.w * sc.w + sh.w;
            }
            float4 g = *(const float4*)(aggr + (size_t)gr * D + k0 + ak4);
            av.x += g.x; av.y += g.y; av.z += g.z; av.w += g.w;
        }
        As[ak4 + 0][arow] = av.x;
        As[ak4 + 1][arow] = av.y;
        As[ak4 + 2][arow] = av.z;
        As[ak4 + 3][arow] = av.w;
#pragma unroll
        for (int c = 0; c < 4; ++c)
            *(float4*)&Bs[bk][c * 64 + bn4] =
                *(const float4*)(W + (size_t)(k0 + bk) * D + c * 64 + bn4);
        __syncthreads();
#pragma unroll
        for (int k = 0; k < 16; ++k) {
            float4 a4 = *(const float4*)&As[k][ty << 2];
            float a[4] = {a4.x, a4.y, a4.z, a4.w};
#pragma unroll
            for (int jc = 0; jc < 4; ++jc) {
                float4 b4 = *(const float4*)&Bs[k][(jc << 6) + (tx << 2)];
#pragma unroll
                for (int i = 0; i < 4; ++i) {
                    acc[i][jc * 4 + 0] += a[i] * b4.x;
                    acc[i][jc * 4 + 1] += a[i] * b4.y;
                    acc[i][jc * 4 + 2] += a[i] * b4.z;
                    acc[i][jc * 4 + 3] += a[i] * b4.w;
                }
            }
        }
        __syncthreads();
    }

    float4 s4[4], q4[4];
#pragma unroll
    for (int jc = 0; jc < 4; ++jc) {
        s4[jc] = make_float4(0.f, 0.f, 0.f, 0.f);
        q4[jc] = make_float4(0.f, 0.f, 0.f, 0.f);
    }
#pragma unroll
    for (int jc = 0; jc < 4; ++jc) {
        int col = (jc << 6) + (tx << 2);
        float4 bias4 = *(const float4*)(bias + col);
#pragma unroll
        for (int i = 0; i < 4; ++i) {
            int gr = m0 + (ty << 2) + i;
            if (gr < rows) {
                float4 o;
                o.x = fmaxf(acc[i][jc * 4 + 0] + bias4.x, 0.f);
                o.y = fmaxf(acc[i][jc * 4 + 1] + bias4.y, 0.f);
                o.z = fmaxf(acc[i][jc * 4 + 2] + bias4.z, 0.f);
                o.w = fmaxf(acc[i][jc * 4 + 3] + bias4.w, 0.f);
                if (ADD_INIT) {
                    float4 iv = *(const float4*)(init + (size_t)gr * D + col);
                    o.x += iv.x; o.y += iv.y; o.z += iv.z; o.w += iv.w;
                }
                if (DO_STATS) {
                    s4[jc].x += o.x; s4[jc].y += o.y;
                    s4[jc].z += o.z; s4[jc].w += o.w;
                    q4[jc].x += o.x * o.x; q4[jc].y += o.y * o.y;
                    q4[jc].z += o.z * o.z; q4[jc].w += o.w * o.w;
                }
                *(float4*)(out + (size_t)gr * D + col) = o;
            }
        }
    }

    if (DO_STATS) {
#pragma unroll
        for (int jc = 0; jc < 4; ++jc)
            *(float4*)&Bs[ty][(jc << 6) + (tx << 2)] = s4[jc];
        __syncthreads();
        {
            float s = 0.f;
#pragma unroll
            for (int t = 0; t < 16; ++t) s += Bs[t][tid];
            atomicAdd(&stats_out[tid], s);
        }
        __syncthreads();
#pragma unroll
        for (int jc = 0; jc < 4; ++jc)
            *(float4*)&Bs[ty][(jc << 6) + (tx << 2)] = q4[jc];
        __syncthreads();
        {
            float s = 0.f;
#pragma unroll
            for (int t = 0; t < 16; ++t) s += Bs[t][tid];
            atomicAdd(&stats_out[D + tid], s);
        }
    }
}

// ----------------------------------------------------------------- launch ----
extern "C" void kernel_launch(void* const* d_in, const int* in_sizes, int n_in,
                              void* d_out, int out_size, void* d_ws, size_t ws_size,
                              hipStream_t stream)
{
    const float* node_feat = (const float*)d_in[0];
    const float* e32       = (const float*)d_in[1];
    const int*   src       = (const int*)d_in[2];
    const int*   dst       = (const int*)d_in[3];
    const float* W_conv    = (const float*)d_in[4];
    const float* b_conv    = (const float*)d_in[5];
    const float* W_edge    = (const float*)d_in[6];
    const float* b_edge    = (const float*)d_in[7];
    const float* gamma     = (const float*)d_in[8];
    const float* beta      = (const float*)d_in[9];
    float*       out       = (float*)d_out;

    const int N = in_sizes[0] / D;
    const int E = in_sizes[2];
    const int L = in_sizes[5] / D;

    float* x          = (float*)d_ws;                  // N*D f32
    float* aggr       = x + (size_t)N * D;             // N*D f32
    float* stats      = aggr + (size_t)N * D;          // L*2*D (slots)
    int*   cnt        = (int*)(stats + (size_t)L * 2 * D); // N
    int*   row_ptr    = cnt + N;                       // N+1
    int*   fillc      = row_ptr + N + 1;               // N
    int*   edge_idx   = fillc + N;                     // E
    int*   src_sorted = edge_idx + E;                  // E
    uintptr_t pa      = ((uintptr_t)(src_sorted + E) + 63) & ~(uintptr_t)63;
    ushort* WTh       = (ushort*)pa;                   // L*D*D bf16 hi
    ushort* WTl       = WTh + (size_t)L * D * D;       // L*D*D bf16 lo
    ushort* es        = WTl + (size_t)L * D * D;       // E*512 (hi|lo rows)

    int nodeBlocks    = (N + 63) / 64;
    int edgeBlocks    = (E + 63) / 64;
    int gatherBlocks  = (N + 3) / 4;
    int eThreadBlocks = (E + 255) / 256;

    // ---- one-time: zero stats slots + CSR + W_edge K-chunk-major hi/lo ----
    hipMemsetAsync(cnt, 0, (size_t)N * sizeof(int), stream);
    hipMemsetAsync(fillc, 0, (size_t)N * sizeof(int), stream);
    hipMemsetAsync(stats, 0, (size_t)L * 2 * D * sizeof(float), stream);
    hist_kernel<<<eThreadBlocks, 256, 0, stream>>>(dst, cnt, E);
    scan_kernel<<<1, 256, 0, stream>>>(cnt, row_ptr, N);
    fill_kernel<<<eThreadBlocks, 256, 0, stream>>>(
        dst, src, row_ptr, fillc, edge_idx, src_sorted, E);
    wconv_kernel<<<L * D, 256, 0, stream>>>(W_edge, WTh, WTl);

    for (int i = 0; i < L; ++i) {
        if (i == 0) {
            gather_l0<<<gatherBlocks, 256, 0, stream>>>(
                node_feat, e32, src, row_ptr, edge_idx, aggr, N);
            gemm_rowfull<false, false, true><<<nodeBlocks, 256, 0, stream>>>(
                node_feat, aggr, W_conv, b_conv, nullptr, nullptr, nullptr,
                nullptr, x, stats, N);
        } else {
            const float* st = stats + (size_t)(i - 1) * 2 * D;
            gather_sorted<<<gatherBlocks, 256, 0, stream>>>(
                x, es, src_sorted, row_ptr, st, gamma + (size_t)(i - 1) * D,
                beta + (size_t)(i - 1) * D, aggr, N);
            gemm_rowfull<true, false, true><<<nodeBlocks, 256, 0, stream>>>(
                x, aggr, W_conv + (size_t)i * D * D, b_conv + (size_t)i * D,
                st, gamma + (size_t)(i - 1) * D, beta + (size_t)(i - 1) * D,
                nullptr, x, stats + (size_t)i * 2 * D, N);
        }
        if (i == 0)
            gemm_edge_mfma<0><<<edgeBlocks, 256, 0, stream>>>(
                e32, edge_idx, nullptr, WTh, WTl, b_edge, es, E);
        else
            gemm_edge_mfma<1><<<edgeBlocks, 256, 0, stream>>>(
                nullptr, nullptr, es, WTh + (size_t)i * D * D,
                WTl + (size_t)i * D * D, b_edge + (size_t)i * D, es, E);
    }

    // final conv: layer L-1 weights on (BN_3(x), gather(es_4)), + node_feat
    {
        const float* st = stats + (size_t)(L - 1) * 2 * D;
        gather_sorted<<<gatherBlocks, 256, 0, stream>>>(
            x, es, src_sorted, row_ptr, st, gamma + (size_t)(L - 1) * D,
            beta + (size_t)(L - 1) * D, aggr, N);
        gemm_rowfull<true, true, false><<<nodeBlocks, 256, 0, stream>>>(
            x, aggr, W_conv + (size_t)(L - 1) * D * D, b_conv + (size_t)(L - 1) * D,
            st, gamma + (size_t)(L - 1) * D, beta + (size_t)(L - 1) * D,
            node_feat, out, nullptr, N);
    }
}

// Round 16
// 1864.019 us; speedup vs baseline: 1.0005x; 1.0005x over previous
//
#include <hip/hip_runtime.h>

// GINEEncoderBlock — round 18: issue-order fix in the edge GEMM K-loop.
// R16+R17 double-null isolated the real serializer: per step the source
// issued A(kc+3) BEFORE W(kc+1); vmcnt retires IN ORDER, so the MFMA's
// wait on W(kc) (issued last step, after that step's A-load) implicitly
// drains the younger... no — drains the OLDER A-load issued just ~1 phase
// (~470cyc) earlier, < es HBM latency (~900cyc) -> ~430cyc stall at every
// MFMA, independent of prefetch depth and barrier flavor. Fix: issue A
// LAST (after the MFMAs): ds_read -> W(kc+1) issue -> MFMA (waits W(kc),
// L2-hot, covered) -> A(kc+3) issue -> stage A(kc+1) (counted wait, ~2
// phases coverage) -> lgkm-only barrier. Hazards unchanged (set kc%3's
// old chunk ds_written at step kc-1 before the overwrite; ds_write reads
// its regs at issue). Pre-registered: neutral => 4-wave structure ceiling.

#define D 256
#define BN_EPS 1e-5f

typedef __attribute__((ext_vector_type(8))) short bf16x8;
typedef __attribute__((ext_vector_type(8))) ushort u16x8;
typedef __attribute__((ext_vector_type(4))) float f32x4;

__device__ __forceinline__ ushort bf16h(float f) {
    uint u = __float_as_uint(f);
    return (ushort)((u + 0x7FFFu + ((u >> 16) & 1u)) >> 16);
}
__device__ __forceinline__ float bf16f(ushort h) {
    return __uint_as_float(((uint)h) << 16);
}

// truncation split: h = top16(f), l = top16(f - h); h+l ~ f to ~2^-16 rel.
__device__ __forceinline__ void split2(float f, ushort& h, ushort& l) {
    uint u = __float_as_uint(f);
    h = (ushort)(u >> 16);
    float r = f - __uint_as_float(u & 0xFFFF0000u);
    l = (ushort)(__float_as_uint(r) >> 16);
}

__device__ __forceinline__ void cvt_write8(const float4& x0, const float4& x1,
                                           ushort* dh, ushort* dl) {
    float f[8] = {x0.x, x0.y, x0.z, x0.w, x1.x, x1.y, x1.z, x1.w};
    u16x8 hv, lv;
#pragma unroll
    for (int j = 0; j < 8; ++j) {
        ushort h, l;
        split2(f[j], h, l);
        hv[j] = h; lv[j] = l;
    }
    *(u16x8*)dh = hv;
    *(u16x8*)dl = lv;
}

// LDS-only barrier: drain own ds ops; leave global loads (register
// destinations, consumption-point waits) in flight.
__device__ __forceinline__ void barrier_lds() {
    asm volatile("s_waitcnt lgkmcnt(0)" ::: "memory");
    __builtin_amdgcn_s_barrier();
}

// ------------------------------------------------------------- CSR build ----
__global__ __launch_bounds__(256) void hist_kernel(
    const int* __restrict__ dst, int* __restrict__ cnt, int E)
{
    int i = blockIdx.x * 256 + threadIdx.x;
    if (i < E) atomicAdd(&cnt[dst[i]], 1);
}

__global__ __launch_bounds__(256) void scan_kernel(
    const int* __restrict__ cnt, int* __restrict__ row_ptr, int N)
{
    __shared__ int buf[256];
    __shared__ int carry_s;
    if (threadIdx.x == 0) { carry_s = 0; row_ptr[0] = 0; }
    __syncthreads();
    for (int base = 0; base < N; base += 256) {
        int i = base + threadIdx.x;
        int v = (i < N) ? cnt[i] : 0;
        buf[threadIdx.x] = v;
        __syncthreads();
#pragma unroll
        for (int off = 1; off < 256; off <<= 1) {
            int t = (threadIdx.x >= off) ? buf[threadIdx.x - off] : 0;
            __syncthreads();
            buf[threadIdx.x] += t;
            __syncthreads();
        }
        int inc = buf[threadIdx.x] + carry_s;
        if (i < N) row_ptr[i + 1] = inc;
        __syncthreads();
        if (threadIdx.x == 255) carry_s = inc;
        __syncthreads();
    }
}

__global__ __launch_bounds__(256) void fill_kernel(
    const int* __restrict__ dst, const int* __restrict__ src,
    const int* __restrict__ row_ptr, int* __restrict__ fillc,
    int* __restrict__ edge_idx, int* __restrict__ src_sorted, int E)
{
    int i = blockIdx.x * 256 + threadIdx.x;
    if (i < E) {
        int d = dst[i];
        int pos = atomicAdd(&fillc[d], 1);
        int slot = row_ptr[d] + pos;
        edge_idx[slot] = i;
        src_sorted[slot] = src[i];
    }
}

// ------------------------------------------------------- gather (layer 0) ----
__global__ __launch_bounds__(256) void gather_l0(
    const float* __restrict__ x, const float* __restrict__ e32,
    const int* __restrict__ src, const int* __restrict__ row_ptr,
    const int* __restrict__ edge_idx, float* __restrict__ aggr, int N)
{
    int node = blockIdx.x * 4 + (threadIdx.x >> 6);
    if (node >= N) return;
    int lane = threadIdx.x & 63;
    int beg = row_ptr[node], end = row_ptr[node + 1];
    float4 acc = make_float4(0.f, 0.f, 0.f, 0.f);
    if (beg < end) {
        int ed0 = edge_idx[beg];
        int s0  = src[ed0];
        float4 e0 = ((const float4*)(e32 + (size_t)ed0 * D))[lane];
        float4 x0 = ((const float4*)(x + (size_t)s0 * D))[lane];
        for (int j = beg + 1; j < end; ++j) {
            int ed1 = edge_idx[j];
            int s1  = src[ed1];
            float4 e1 = ((const float4*)(e32 + (size_t)ed1 * D))[lane];
            float4 x1 = ((const float4*)(x + (size_t)s1 * D))[lane];
            acc.x += fmaxf(e0.x + x0.x, 0.f);
            acc.y += fmaxf(e0.y + x0.y, 0.f);
            acc.z += fmaxf(e0.z + x0.z, 0.f);
            acc.w += fmaxf(e0.w + x0.w, 0.f);
            e0 = e1; x0 = x1;
        }
        acc.x += fmaxf(e0.x + x0.x, 0.f);
        acc.y += fmaxf(e0.y + x0.y, 0.f);
        acc.z += fmaxf(e0.z + x0.z, 0.f);
        acc.w += fmaxf(e0.w + x0.w, 0.f);
    }
    ((float4*)(aggr + (size_t)node * D))[lane] = acc;
}

// ------------------------------------------------- gather (sorted, BN-x) ----
__global__ __launch_bounds__(256) void gather_sorted(
    const float* __restrict__ x, const ushort* __restrict__ es,
    const int* __restrict__ src_sorted, const int* __restrict__ row_ptr,
    const float* __restrict__ stats, const float* __restrict__ gamma,
    const float* __restrict__ beta, float* __restrict__ aggr, int N)
{
    __shared__ float ssc[256], ssf[256];
    {
        int c = threadIdx.x;
        float inv_n = 1.f / (float)N;
        float mean = stats[c] * inv_n;
        float var  = stats[D + c] * inv_n - mean * mean;
        float sc = gamma[c] * rsqrtf(var + BN_EPS);
        ssc[c] = sc;
        ssf[c] = beta[c] - mean * sc;
    }
    __syncthreads();
    int node = blockIdx.x * 4 + (threadIdx.x >> 6);
    if (node >= N) return;
    int lane = threadIdx.x & 63;
    float4 sc4 = *(const float4*)&ssc[lane * 4];
    float4 sh4 = *(const float4*)&ssf[lane * 4];
    int beg = row_ptr[node], end = row_ptr[node + 1];
    float4 acc = make_float4(0.f, 0.f, 0.f, 0.f);
    if (beg < end) {
        int s0 = src_sorted[beg];
        const ushort* er0 = es + (size_t)beg * 512;
        ushort4 hv0 = *(const ushort4*)(er0 + lane * 4);
        ushort4 lv0 = *(const ushort4*)(er0 + 256 + lane * 4);
        float4  xv0 = ((const float4*)(x + (size_t)s0 * D))[lane];
        for (int j = beg + 1; j < end; ++j) {
            int s1 = src_sorted[j];
            const ushort* er1 = es + (size_t)j * 512;
            ushort4 hv1 = *(const ushort4*)(er1 + lane * 4);
            ushort4 lv1 = *(const ushort4*)(er1 + 256 + lane * 4);
            float4  xv1 = ((const float4*)(x + (size_t)s1 * D))[lane];
            float4 ev;
            ev.x = bf16f(hv0.x) + bf16f(lv0.x);
            ev.y = bf16f(hv0.y) + bf16f(lv0.y);
            ev.z = bf16f(hv0.z) + bf16f(lv0.z);
            ev.w = bf16f(hv0.w) + bf16f(lv0.w);
            acc.x += fmaxf(xv0.x * sc4.x + sh4.x + ev.x, 0.f);
            acc.y += fmaxf(xv0.y * sc4.y + sh4.y + ev.y, 0.f);
            acc.z += fmaxf(xv0.z * sc4.z + sh4.z + ev.z, 0.f);
            acc.w += fmaxf(xv0.w * sc4.w + sh4.w + ev.w, 0.f);
            hv0 = hv1; lv0 = lv1; xv0 = xv1;
        }
        float4 ev;
        ev.x = bf16f(hv0.x) + bf16f(lv0.x);
        ev.y = bf16f(hv0.y) + bf16f(lv0.y);
        ev.z = bf16f(hv0.z) + bf16f(lv0.z);
        ev.w = bf16f(hv0.w) + bf16f(lv0.w);
        acc.x += fmaxf(xv0.x * sc4.x + sh4.x + ev.x, 0.f);
        acc.y += fmaxf(xv0.y * sc4.y + sh4.y + ev.y, 0.f);
        acc.z += fmaxf(xv0.z * sc4.z + sh4.z + ev.z, 0.f);
        acc.w += fmaxf(xv0.w * sc4.w + sh4.w + ev.w, 0.f);
    }
    ((float4*)(aggr + (size_t)node * D))[lane] = acc;
}

// ------------------------------------------- W -> K-chunk-major bf16 hi/lo --
__global__ __launch_bounds__(256) void wconv_kernel(
    const float* __restrict__ W, ushort* __restrict__ WTh,
    ushort* __restrict__ WTl)
{
    int bk = blockIdx.x;            // layer*D + k
    int col = threadIdx.x;
    int layer = bk >> 8, k = bk & 255;
    float v = W[(size_t)bk * D + col];
    ushort h = bf16h(v);
    ushort lo = bf16h(v - bf16f(h));
    size_t o = (((size_t)layer * 8 + (k >> 5)) * 256 + col) * 32 + (k & 31);
    WTh[o] = h;
    WTl[o] = lo;
}

// ----------------------------------------------------- MFMA edge GEMM -------
// R17 structure, K-step reordered: ds_read -> W(kc+1) issue -> MFMA ->
// A(kc+3) issue -> stage A(kc+1) -> lgkm barrier. 64x256/block, 4 waves,
// 4x4 16x16x32 frags, hi/lo 3-MFMA; MODE 0 = permuted fp32 (cvt staging),
// MODE 1 = es linear in-place. LDS union 34.8KB; epilogue Tr transpose.
template<int MODE>
__global__ __launch_bounds__(256) void gemm_edge_mfma(
    const float* __restrict__ e32, const int* __restrict__ edge_idx,
    const ushort* __restrict__ esin, const ushort* __restrict__ WTh,
    const ushort* __restrict__ WTl, const float* __restrict__ bias,
    ushort* __restrict__ es, int rows)
{
    __shared__ char smem[34816];
    ushort* AhB = (ushort*)smem;              // [2][64][40]
    ushort* AlB = (ushort*)(smem + 10240);    // [2][64][40]
    float*  TrB = (float*)smem;               // [4][32][68] (epilogue reuse)
#define AH(b, r, c) AhB[(b) * 2560 + (r) * 40 + (c)]
#define AL(b, r, c) AlB[(b) * 2560 + (r) * 40 + (c)]
#define TR(w, r, c) TrB[(w) * 2176 + (r) * 68 + (c)]

    const int tid  = threadIdx.x;
    const int lane = tid & 63;
    const int wave = tid >> 6;
    const int m0   = blockIdx.x * 64;
    const int l15  = lane & 15;
    const int l4   = lane >> 4;
    const int wcol = wave * 64;

    const int srow = tid >> 2;    // 0..63
    const int ssec = tid & 3;     // 8-elem sector
    const int sgr  = m0 + srow;
    const bool svalid = (sgr < rows);

    f32x4 acc[4][4];
#pragma unroll
    for (int m = 0; m < 4; ++m)
#pragma unroll
        for (int n = 0; n < 4; ++n) acc[m][n] = (f32x4){0.f, 0.f, 0.f, 0.f};

    float4 pf0[3] = {}, pf1[3] = {};      // MODE0 prefetch sets (3-deep)
    u16x8  ph[3] = {}, pl[3] = {};        // MODE1 prefetch sets (3-deep)
    bf16x8 bh[4], bl[4], bhn[4], bln[4];

    const float*  a32 = nullptr;
    const ushort* ahi = nullptr;
    if (MODE == 0) {
        int erow = svalid ? edge_idx[sgr] : 0;
        a32 = e32 + (size_t)erow * D + ssec * 8;
    } else {
        ahi = esin + (size_t)sgr * 512 + ssec * 8;   // lo at +256
    }

    // ---- prologue: W chunk 0 first, then A chunks 0,1,2; stage chunk 0 ----
#pragma unroll
    for (int n = 0; n < 4; ++n) {
        size_t o = ((size_t)(wcol + n * 16 + l15)) * 32 + l4 * 8;
        bh[n] = *(const bf16x8*)(WTh + o);
        bl[n] = *(const bf16x8*)(WTl + o);
    }
    if (svalid) {
#pragma unroll
        for (int c = 0; c < 3; ++c) {
            if (MODE == 0) {
                const float* p = a32 + c * 32;
                pf0[c] = *(const float4*)p;
                pf1[c] = *(const float4*)(p + 4);
            } else {
                ph[c] = *(const u16x8*)(ahi + c * 32);
                pl[c] = *(const u16x8*)(ahi + 256 + c * 32);
            }
        }
    }
    if (MODE == 0) {
        cvt_write8(pf0[0], pf1[0], &AH(0, srow, ssec * 8), &AL(0, srow, ssec * 8));
    } else {
        *(u16x8*)&AH(0, srow, ssec * 8) = ph[0];
        *(u16x8*)&AL(0, srow, ssec * 8) = pl[0];
    }
    barrier_lds();

    // ---- K loop: ds_read -> W issue -> MFMA -> A issue -> stage -> bar ----
#pragma unroll
    for (int kc = 0; kc < 8; ++kc) {
        const int cur = kc & 1;
        // 1. own fragments from LDS
        bf16x8 ah[4], al[4];
#pragma unroll
        for (int m = 0; m < 4; ++m) {
            ah[m] = *(const bf16x8*)&AH(cur, m * 16 + l15, l4 * 8);
            al[m] = *(const bf16x8*)&AL(cur, m * 16 + l15, l4 * 8);
        }
        // 2. issue W(kc+1) — oldest outstanding loads stay W-only
        if (kc < 7) {
#pragma unroll
            for (int n = 0; n < 4; ++n) {
                size_t o = ((size_t)(kc + 1) * 256 + wcol + n * 16 + l15) * 32 + l4 * 8;
                bhn[n] = *(const bf16x8*)(WTh + o);
                bln[n] = *(const bf16x8*)(WTl + o);
            }
        }
        // 3. MFMA: waits W(kc) (L2-hot, issued last step before any A)
#pragma unroll
        for (int m = 0; m < 4; ++m)
#pragma unroll
            for (int n = 0; n < 4; ++n) {
                acc[m][n] = __builtin_amdgcn_mfma_f32_16x16x32_bf16(
                    ah[m], bh[n], acc[m][n], 0, 0, 0);
                acc[m][n] = __builtin_amdgcn_mfma_f32_16x16x32_bf16(
                    ah[m], bl[n], acc[m][n], 0, 0, 0);
                acc[m][n] = __builtin_amdgcn_mfma_f32_16x16x32_bf16(
                    al[m], bh[n], acc[m][n], 0, 0, 0);
            }
        // 4. issue A(kc+3) into set kc%3 (youngest loads; survive 2+ phases)
        if (kc < 5 && svalid) {
            if (MODE == 0) {
                const float* p = a32 + (kc + 3) * 32;
                pf0[kc % 3] = *(const float4*)p;
                pf1[kc % 3] = *(const float4*)(p + 4);
            } else {
                ph[kc % 3] = *(const u16x8*)(ahi + (kc + 3) * 32);
                pl[kc % 3] = *(const u16x8*)(ahi + 256 + (kc + 3) * 32);
            }
        }
        // 5. stage A(kc+1) from set (kc+1)%3 (counted vmcnt wait)
        if (kc < 7) {
            const int ns = (kc + 1) % 3;
            if (MODE == 0) {
                cvt_write8(pf0[ns], pf1[ns],
                           &AH(cur ^ 1, srow, ssec * 8), &AL(cur ^ 1, srow, ssec * 8));
            } else {
                *(u16x8*)&AH(cur ^ 1, srow, ssec * 8) = ph[ns];
                *(u16x8*)&AL(cur ^ 1, srow, ssec * 8) = pl[ns];
            }
#pragma unroll
            for (int n = 0; n < 4; ++n) { bh[n] = bhn[n]; bl[n] = bln[n]; }
        }
        barrier_lds();
    }

    // ---- epilogue: bias+relu -> LDS transpose -> es row stores ----
#pragma unroll
    for (int h = 0; h < 2; ++h) {
        __syncthreads();
#pragma unroll
        for (int mm = 0; mm < 2; ++mm) {
            int m = h * 2 + mm;
#pragma unroll
            for (int n = 0; n < 4; ++n) {
                float bv = bias[wcol + n * 16 + l15];
#pragma unroll
                for (int r = 0; r < 4; ++r)
                    TR(wave, mm * 16 + l4 * 4 + r, n * 16 + l15) =
                        fmaxf(acc[m][n][r] + bv, 0.f);
            }
        }
        __syncthreads();
#pragma unroll
        for (int p = 0; p < 8; ++p) {
            int row  = p * 4 + l4;
            int grow = m0 + h * 32 + row;
            if (grow < rows) {
                float4 v = *(const float4*)&TR(wave, row, l15 * 4);
                ushort4 h4, l4v;
                split2(v.x, h4.x, l4v.x);
                split2(v.y, h4.y, l4v.y);
                split2(v.z, h4.z, l4v.z);
                split2(v.w, h4.w, l4v.w);
                size_t off = (size_t)grow * 512 + wcol + l15 * 4;
                *(ushort4*)(es + off) = h4;
                *(ushort4*)(es + off + 256) = l4v;
            }
        }
    }
#undef AH
#undef AL
#undef TR
}

// ------------------------------------------------------------------- GEMM ----
// fp32 row-full GEMM for node convs (N=10k). BN_A: scale/shift inline in
// LDS from stats_in+gamma/beta. DO_STATS: column sum/sumsq into stats_out.
template<bool BN_A, bool ADD_INIT, bool DO_STATS>
__global__ __launch_bounds__(256) void gemm_rowfull(
    const float* A, const float* __restrict__ aggr,
    const float* __restrict__ W, const float* __restrict__ bias,
    const float* __restrict__ stats_in, const float* __restrict__ gamma,
    const float* __restrict__ beta, const float* __restrict__ init,
    float* out, float* __restrict__ stats_out, int rows)
{
    __shared__ float As[16][68];
    __shared__ float Bs[16][260];
    __shared__ float ssc[256], ssf[256];

    const int tid = threadIdx.x;
    const int m0 = blockIdx.x * 64;
    const int tx = tid & 15;
    const int ty = tid >> 4;

    const int arow = tid >> 2;
    const int ak4  = (tid & 3) << 2;
    const int bk   = tid >> 4;
    const int bn4  = (tid & 15) << 2;

    if (BN_A) {
        float inv_n = 1.f / (float)rows;
        float mean = stats_in[tid] * inv_n;
        float var  = stats_in[D + tid] * inv_n - mean * mean;
        float sc = gamma[tid] * rsqrtf(var + BN_EPS);
        ssc[tid] = sc;
        ssf[tid] = beta[tid] - mean * sc;
        __syncthreads();
    }

    float acc[4][16];
#pragma unroll
    for (int i = 0; i < 4; ++i)
#pragma unroll
        for (int j = 0; j < 16; ++j) acc[i][j] = 0.f;

    for (int k0 = 0; k0 < D; k0 += 16) {
        float4 av = make_float4(0.f, 0.f, 0.f, 0.f);
        int gr = m0 + arow;
        if (gr < rows) {
            av = *(const float4*)(A + (size_t)gr * D + k0 + ak4);
            if (BN_A) {
                float4 sc = *(const float4*)&ssc[k0 + ak4];
                float4 sh = *(const float4*)&ssf[k0 + ak4];
                av.x = av.x * sc.x + sh.x;
                av.y = av.y * sc.y + sh.y;
                av.z = av.z * sc.z + sh.z;
                av.w = av.w * sc.w + sh.w;
            }
            float4 g = *(const float4*)(aggr + (size_t)gr * D + k0 + ak4);
            av.x += g.x; av.y += g.y; av.z += g.z; av.w += g.w;
        }
        As[ak4 + 0][arow] = av.x;
        As[ak4 + 1][arow] = av.y;
        As[ak4 + 2][arow] = av.z;
        As[ak4 + 3][arow] = av.w;
#pragma unroll
        for (int c = 0; c < 4; ++c)
            *(float4*)&Bs[bk][c * 64 + bn4] =
                *(const float4*)(W + (size_t)(k0 + bk) * D + c * 64 + bn4);
        __syncthreads();
#pragma unroll
        for (int k = 0; k < 16; ++k) {
            float4 a4 = *(const float4*)&As[k][ty << 2];
            float a[4] = {a4.x, a4.y, a4.z, a4.w};
#pragma unroll
            for (int jc = 0; jc < 4; ++jc) {
                float4 b4 = *(const float4*)&Bs[k][(jc << 6) + (tx << 2)];
#pragma unroll
                for (int i = 0; i < 4; ++i) {
                    acc[i][jc * 4 + 0] += a[i] * b4.x;
                    acc[i][jc * 4 + 1] += a[i] * b4.y;
                    acc[i][jc * 4 + 2] += a[i] * b4.z;
                    acc[i][jc * 4 + 3] += a[i] * b4.w;
                }
            }
        }
        __syncthreads();
    }

    float4 s4[4], q4[4];
#pragma unroll
    for (int jc = 0; jc < 4; ++jc) {
        s4[jc] = make_float4(0.f, 0.f, 0.f, 0.f);
        q4[jc] = make_float4(0.f, 0.f, 0.f, 0.f);
    }
#pragma unroll
    for (int jc = 0; jc < 4; ++jc) {
        int col = (jc << 6) + (tx << 2);
        float4 bias4 = *(const float4*)(bias + col);
#pragma unroll
        for (int i = 0; i < 4; ++i) {
            int gr = m0 + (ty << 2) + i;
            if (gr < rows) {
                float4 o;
                o.x = fmaxf(acc[i][jc * 4 + 0] + bias4.x, 0.f);
                o.y = fmaxf(acc[i][jc * 4 + 1] + bias4.y, 0.f);
                o.z = fmaxf(acc[i][jc * 4 + 2] + bias4.z, 0.f);
                o.w = fmaxf(acc[i][jc * 4 + 3] + bias4.w, 0.f);
                if (ADD_INIT) {
                    float4 iv = *(const float4*)(init + (size_t)gr * D + col);
                    o.x += iv.x; o.y += iv.y; o.z += iv.z; o.w += iv.w;
                }
                if (DO_STATS) {
                    s4[jc].x += o.x; s4[jc].y += o.y;
                    s4[jc].z += o.z; s4[jc].w += o.w;
                    q4[jc].x += o.x * o.x; q4[jc].y += o.y * o.y;
                    q4[jc].z += o.z * o.z; q4[jc].w += o.w * o.w;
                }
                *(float4*)(out + (size_t)gr * D + col) = o;
            }
        }
    }

    if (DO_STATS) {
#pragma unroll
        for (int jc = 0; jc < 4; ++jc)
            *(float4*)&Bs[ty][(jc << 6) + (tx << 2)] = s4[jc];
        __syncthreads();
        {
            float s = 0.f;
#pragma unroll
            for (int t = 0; t < 16; ++t) s += Bs[t][tid];
            atomicAdd(&stats_out[tid], s);
        }
        __syncthreads();
#pragma unroll
        for (int jc = 0; jc < 4; ++jc)
            *(float4*)&Bs[ty][(jc << 6) + (tx << 2)] = q4[jc];
        __syncthreads();
        {
            float s = 0.f;
#pragma unroll
            for (int t = 0; t < 16; ++t) s += Bs[t][tid];
            atomicAdd(&stats_out[D + tid], s);
        }
    }
}

// ----------------------------------------------------------------- launch ----
extern "C" void kernel_launch(void* const* d_in, const int* in_sizes, int n_in,
                              void* d_out, int out_size, void* d_ws, size_t ws_size,
                              hipStream_t stream)
{
    const float* node_feat = (const float*)d_in[0];
    const float* e32       = (const float*)d_in[1];
    const int*   src       = (const int*)d_in[2];
    const int*   dst       = (const int*)d_in[3];
    const float* W_conv    = (const float*)d_in[4];
    const float* b_conv    = (const float*)d_in[5];
    const float* W_edge    = (const float*)d_in[6];
    const float* b_edge    = (const float*)d_in[7];
    const float* gamma     = (const float*)d_in[8];
    const float* beta      = (const float*)d_in[9];
    float*       out       = (float*)d_out;

    const int N = in_sizes[0] / D;
    const int E = in_sizes[2];
    const int L = in_sizes[5] / D;

    float* x          = (float*)d_ws;                  // N*D f32
    float* aggr       = x + (size_t)N * D;             // N*D f32
    float* stats      = aggr + (size_t)N * D;          // L*2*D (slots)
    int*   cnt        = (int*)(stats + (size_t)L * 2 * D); // N
    int*   row_ptr    = cnt + N;                       // N+1
    int*   fillc      = row_ptr + N + 1;               // N
    int*   edge_idx   = fillc + N;                     // E
    int*   src_sorted = edge_idx + E;                  // E
    uintptr_t pa      = ((uintptr_t)(src_sorted + E) + 63) & ~(uintptr_t)63;
    ushort* WTh       = (ushort*)pa;                   // L*D*D bf16 hi
    ushort* WTl       = WTh + (size_t)L * D * D;       // L*D*D bf16 lo
    ushort* es        = WTl + (size_t)L * D * D;       // E*512 (hi|lo rows)

    int nodeBlocks    = (N + 63) / 64;
    int edgeBlocks    = (E + 63) / 64;
    int gatherBlocks  = (N + 3) / 4;
    int eThreadBlocks = (E + 255) / 256;

    // ---- one-time: zero stats slots + CSR + W_edge K-chunk-major hi/lo ----
    hipMemsetAsync(cnt, 0, (size_t)N * sizeof(int), stream);
    hipMemsetAsync(fillc, 0, (size_t)N * sizeof(int), stream);
    hipMemsetAsync(stats, 0, (size_t)L * 2 * D * sizeof(float), stream);
    hist_kernel<<<eThreadBlocks, 256, 0, stream>>>(dst, cnt, E);
    scan_kernel<<<1, 256, 0, stream>>>(cnt, row_ptr, N);
    fill_kernel<<<eThreadBlocks, 256, 0, stream>>>(
        dst, src, row_ptr, fillc, edge_idx, src_sorted, E);
    wconv_kernel<<<L * D, 256, 0, stream>>>(W_edge, WTh, WTl);

    for (int i = 0; i < L; ++i) {
        if (i == 0) {
            gather_l0<<<gatherBlocks, 256, 0, stream>>>(
                node_feat, e32, src, row_ptr, edge_idx, aggr, N);
            gemm_rowfull<false, false, true><<<nodeBlocks, 256, 0, stream>>>(
                node_feat, aggr, W_conv, b_conv, nullptr, nullptr, nullptr,
                nullptr, x, stats, N);
        } else {
            const float* st = stats + (size_t)(i - 1) * 2 * D;
            gather_sorted<<<gatherBlocks, 256, 0, stream>>>(
                x, es, src_sorted, row_ptr, st, gamma + (size_t)(i - 1) * D,
                beta + (size_t)(i - 1) * D, aggr, N);
            gemm_rowfull<true, false, true><<<nodeBlocks, 256, 0, stream>>>(
                x, aggr, W_conv + (size_t)i * D * D, b_conv + (size_t)i * D,
                st, gamma + (size_t)(i - 1) * D, beta + (size_t)(i - 1) * D,
                nullptr, x, stats + (size_t)i * 2 * D, N);
        }
        if (i == 0)
            gemm_edge_mfma<0><<<edgeBlocks, 256, 0, stream>>>(
                e32, edge_idx, nullptr, WTh, WTl, b_edge, es, E);
        else
            gemm_edge_mfma<1><<<edgeBlocks, 256, 0, stream>>>(
                nullptr, nullptr, es, WTh + (size_t)i * D * D,
                WTl + (size_t)i * D * D, b_edge + (size_t)i * D, es, E);
    }

    // final conv: layer L-1 weights on (BN_3(x), gather(es_4)), + node_feat
    {
        const float* st = stats + (size_t)(L - 1) * 2 * D;
        gather_sorted<<<gatherBlocks, 256, 0, stream>>>(
            x, es, src_sorted, row_ptr, st, gamma + (size_t)(L - 1) * D,
            beta + (size_t)(L - 1) * D, aggr, N);
        gemm_rowfull<true, true, false><<<nodeBlocks, 256, 0, stream>>>(
            x, aggr, W_conv + (size_t)(L - 1) * D * D, b_conv + (size_t)(L - 1) * D,
            st, gamma + (size_t)(L - 1) * D, beta + (size_t)(L - 1) * D,
            node_feat, out, nullptr, N);
    }
}

// Round 17
// 1828.764 us; speedup vs baseline: 1.0198x; 1.0193x over previous
//
#include <hip/hip_runtime.h>

// GINEEncoderBlock — FINAL (round 19): exact revert to the session-best
// configuration (R16, measured 1832.7us; R15 1833.5 — identical within
// noise). R16/R17/R18 triple-null (prefetch depth, barrier semantics,
// issue order all neutral) establishes the 2-barrier-per-K-step edge GEMM
// structure's ceiling at ~186us: the LLVM scheduler canonicalizes all
// source orderings; the residual stall is the structure's serial chain
// (m97-class), breakable only by an 8-phase counted-vmcnt rewrite.
// Session: 3971 -> 1833us (2.17x) via bank-conflict fix, bf16 hi/lo
// 3-MFMA edge GEMM, dst-sorted plane storage, BN fusion.

#define D 256
#define BN_EPS 1e-5f

typedef __attribute__((ext_vector_type(8))) short bf16x8;
typedef __attribute__((ext_vector_type(8))) ushort u16x8;
typedef __attribute__((ext_vector_type(4))) float f32x4;

__device__ __forceinline__ ushort bf16h(float f) {
    uint u = __float_as_uint(f);
    return (ushort)((u + 0x7FFFu + ((u >> 16) & 1u)) >> 16);
}
__device__ __forceinline__ float bf16f(ushort h) {
    return __uint_as_float(((uint)h) << 16);
}

// truncation split: h = top16(f), l = top16(f - h); h+l ~ f to ~2^-16 rel.
__device__ __forceinline__ void split2(float f, ushort& h, ushort& l) {
    uint u = __float_as_uint(f);
    h = (ushort)(u >> 16);
    float r = f - __uint_as_float(u & 0xFFFF0000u);
    l = (ushort)(__float_as_uint(r) >> 16);
}

__device__ __forceinline__ void cvt_write8(const float4& x0, const float4& x1,
                                           ushort* dh, ushort* dl) {
    float f[8] = {x0.x, x0.y, x0.z, x0.w, x1.x, x1.y, x1.z, x1.w};
    u16x8 hv, lv;
#pragma unroll
    for (int j = 0; j < 8; ++j) {
        ushort h, l;
        split2(f[j], h, l);
        hv[j] = h; lv[j] = l;
    }
    *(u16x8*)dh = hv;
    *(u16x8*)dl = lv;
}

// ------------------------------------------------------------- CSR build ----
__global__ __launch_bounds__(256) void hist_kernel(
    const int* __restrict__ dst, int* __restrict__ cnt, int E)
{
    int i = blockIdx.x * 256 + threadIdx.x;
    if (i < E) atomicAdd(&cnt[dst[i]], 1);
}

__global__ __launch_bounds__(256) void scan_kernel(
    const int* __restrict__ cnt, int* __restrict__ row_ptr, int N)
{
    __shared__ int buf[256];
    __shared__ int carry_s;
    if (threadIdx.x == 0) { carry_s = 0; row_ptr[0] = 0; }
    __syncthreads();
    for (int base = 0; base < N; base += 256) {
        int i = base + threadIdx.x;
        int v = (i < N) ? cnt[i] : 0;
        buf[threadIdx.x] = v;
        __syncthreads();
#pragma unroll
        for (int off = 1; off < 256; off <<= 1) {
            int t = (threadIdx.x >= off) ? buf[threadIdx.x - off] : 0;
            __syncthreads();
            buf[threadIdx.x] += t;
            __syncthreads();
        }
        int inc = buf[threadIdx.x] + carry_s;
        if (i < N) row_ptr[i + 1] = inc;
        __syncthreads();
        if (threadIdx.x == 255) carry_s = inc;
        __syncthreads();
    }
}

__global__ __launch_bounds__(256) void fill_kernel(
    const int* __restrict__ dst, const int* __restrict__ src,
    const int* __restrict__ row_ptr, int* __restrict__ fillc,
    int* __restrict__ edge_idx, int* __restrict__ src_sorted, int E)
{
    int i = blockIdx.x * 256 + threadIdx.x;
    if (i < E) {
        int d = dst[i];
        int pos = atomicAdd(&fillc[d], 1);
        int slot = row_ptr[d] + pos;
        edge_idx[slot] = i;
        src_sorted[slot] = src[i];
    }
}

// ------------------------------------------------------- gather (layer 0) ----
__global__ __launch_bounds__(256) void gather_l0(
    const float* __restrict__ x, const float* __restrict__ e32,
    const int* __restrict__ src, const int* __restrict__ row_ptr,
    const int* __restrict__ edge_idx, float* __restrict__ aggr, int N)
{
    int node = blockIdx.x * 4 + (threadIdx.x >> 6);
    if (node >= N) return;
    int lane = threadIdx.x & 63;
    int beg = row_ptr[node], end = row_ptr[node + 1];
    float4 acc = make_float4(0.f, 0.f, 0.f, 0.f);
    if (beg < end) {
        int ed0 = edge_idx[beg];
        int s0  = src[ed0];
        float4 e0 = ((const float4*)(e32 + (size_t)ed0 * D))[lane];
        float4 x0 = ((const float4*)(x + (size_t)s0 * D))[lane];
        for (int j = beg + 1; j < end; ++j) {
            int ed1 = edge_idx[j];
            int s1  = src[ed1];
            float4 e1 = ((const float4*)(e32 + (size_t)ed1 * D))[lane];
            float4 x1 = ((const float4*)(x + (size_t)s1 * D))[lane];
            acc.x += fmaxf(e0.x + x0.x, 0.f);
            acc.y += fmaxf(e0.y + x0.y, 0.f);
            acc.z += fmaxf(e0.z + x0.z, 0.f);
            acc.w += fmaxf(e0.w + x0.w, 0.f);
            e0 = e1; x0 = x1;
        }
        acc.x += fmaxf(e0.x + x0.x, 0.f);
        acc.y += fmaxf(e0.y + x0.y, 0.f);
        acc.z += fmaxf(e0.z + x0.z, 0.f);
        acc.w += fmaxf(e0.w + x0.w, 0.f);
    }
    ((float4*)(aggr + (size_t)node * D))[lane] = acc;
}

// ------------------------------------------------- gather (sorted, BN-x) ----
__global__ __launch_bounds__(256) void gather_sorted(
    const float* __restrict__ x, const ushort* __restrict__ es,
    const int* __restrict__ src_sorted, const int* __restrict__ row_ptr,
    const float* __restrict__ stats, const float* __restrict__ gamma,
    const float* __restrict__ beta, float* __restrict__ aggr, int N)
{
    __shared__ float ssc[256], ssf[256];
    {
        int c = threadIdx.x;
        float inv_n = 1.f / (float)N;
        float mean = stats[c] * inv_n;
        float var  = stats[D + c] * inv_n - mean * mean;
        float sc = gamma[c] * rsqrtf(var + BN_EPS);
        ssc[c] = sc;
        ssf[c] = beta[c] - mean * sc;
    }
    __syncthreads();
    int node = blockIdx.x * 4 + (threadIdx.x >> 6);
    if (node >= N) return;
    int lane = threadIdx.x & 63;
    float4 sc4 = *(const float4*)&ssc[lane * 4];
    float4 sh4 = *(const float4*)&ssf[lane * 4];
    int beg = row_ptr[node], end = row_ptr[node + 1];
    float4 acc = make_float4(0.f, 0.f, 0.f, 0.f);
    if (beg < end) {
        int s0 = src_sorted[beg];
        const ushort* er0 = es + (size_t)beg * 512;
        ushort4 hv0 = *(const ushort4*)(er0 + lane * 4);
        ushort4 lv0 = *(const ushort4*)(er0 + 256 + lane * 4);
        float4  xv0 = ((const float4*)(x + (size_t)s0 * D))[lane];
        for (int j = beg + 1; j < end; ++j) {
            int s1 = src_sorted[j];
            const ushort* er1 = es + (size_t)j * 512;
            ushort4 hv1 = *(const ushort4*)(er1 + lane * 4);
            ushort4 lv1 = *(const ushort4*)(er1 + 256 + lane * 4);
            float4  xv1 = ((const float4*)(x + (size_t)s1 * D))[lane];
            float4 ev;
            ev.x = bf16f(hv0.x) + bf16f(lv0.x);
            ev.y = bf16f(hv0.y) + bf16f(lv0.y);
            ev.z = bf16f(hv0.z) + bf16f(lv0.z);
            ev.w = bf16f(hv0.w) + bf16f(lv0.w);
            acc.x += fmaxf(xv0.x * sc4.x + sh4.x + ev.x, 0.f);
            acc.y += fmaxf(xv0.y * sc4.y + sh4.y + ev.y, 0.f);
            acc.z += fmaxf(xv0.z * sc4.z + sh4.z + ev.z, 0.f);
            acc.w += fmaxf(xv0.w * sc4.w + sh4.w + ev.w, 0.f);
            hv0 = hv1; lv0 = lv1; xv0 = xv1;
        }
        float4 ev;
        ev.x = bf16f(hv0.x) + bf16f(lv0.x);
        ev.y = bf16f(hv0.y) + bf16f(lv0.y);
        ev.z = bf16f(hv0.z) + bf16f(lv0.z);
        ev.w = bf16f(hv0.w) + bf16f(lv0.w);
        acc.x += fmaxf(xv0.x * sc4.x + sh4.x + ev.x, 0.f);
        acc.y += fmaxf(xv0.y * sc4.y + sh4.y + ev.y, 0.f);
        acc.z += fmaxf(xv0.z * sc4.z + sh4.z + ev.z, 0.f);
        acc.w += fmaxf(xv0.w * sc4.w + sh4.w + ev.w, 0.f);
    }
    ((float4*)(aggr + (size_t)node * D))[lane] = acc;
}

// ------------------------------------------- W -> K-chunk-major bf16 hi/lo --
__global__ __launch_bounds__(256) void wconv_kernel(
    const float* __restrict__ W, ushort* __restrict__ WTh,
    ushort* __restrict__ WTl)
{
    int bk = blockIdx.x;            // layer*D + k
    int col = threadIdx.x;
    int layer = bk >> 8, k = bk & 255;
    float v = W[(size_t)bk * D + col];
    ushort h = bf16h(v);
    ushort lo = bf16h(v - bf16f(h));
    size_t o = (((size_t)layer * 8 + (k >> 5)) * 256 + col) * 32 + (k & 31);
    WTh[o] = h;
    WTl[o] = lo;
}

// ----------------------------------------------------- MFMA edge GEMM -------
// Session-best structure: 64x256/block, 4 waves, 4x4 16x16x32 frags, hi/lo
// 3-MFMA; MODE 0 = permuted fp32 input (cvt staging), MODE 1 = es linear
// in-place; A 3-deep (mod 3) / W 1-deep prefetch, one barrier per K-step;
// LDS union 34.8KB; epilogue Tr transpose -> es rows [256 hi][256 lo].
template<int MODE>
__global__ __launch_bounds__(256) void gemm_edge_mfma(
    const float* __restrict__ e32, const int* __restrict__ edge_idx,
    const ushort* __restrict__ esin, const ushort* __restrict__ WTh,
    const ushort* __restrict__ WTl, const float* __restrict__ bias,
    ushort* __restrict__ es, int rows)
{
    __shared__ char smem[34816];
    ushort* AhB = (ushort*)smem;              // [2][64][40]
    ushort* AlB = (ushort*)(smem + 10240);    // [2][64][40]
    float*  TrB = (float*)smem;               // [4][32][68] (epilogue reuse)
#define AH(b, r, c) AhB[(b) * 2560 + (r) * 40 + (c)]
#define AL(b, r, c) AlB[(b) * 2560 + (r) * 40 + (c)]
#define TR(w, r, c) TrB[(w) * 2176 + (r) * 68 + (c)]

    const int tid  = threadIdx.x;
    const int lane = tid & 63;
    const int wave = tid >> 6;
    const int m0   = blockIdx.x * 64;
    const int l15  = lane & 15;
    const int l4   = lane >> 4;
    const int wcol = wave * 64;

    const int srow = tid >> 2;    // 0..63
    const int ssec = tid & 3;     // 8-elem sector
    const int sgr  = m0 + srow;
    const bool svalid = (sgr < rows);

    f32x4 acc[4][4];
#pragma unroll
    for (int m = 0; m < 4; ++m)
#pragma unroll
        for (int n = 0; n < 4; ++n) acc[m][n] = (f32x4){0.f, 0.f, 0.f, 0.f};

    float4 pf0[3] = {}, pf1[3] = {};      // MODE0 prefetch sets (3-deep)
    u16x8  ph[3] = {}, pl[3] = {};        // MODE1 prefetch sets (3-deep)
    bf16x8 bh[4], bl[4], bhn[4], bln[4];

    const float*  a32 = nullptr;
    const ushort* ahi = nullptr;
    if (MODE == 0) {
        int erow = svalid ? edge_idx[sgr] : 0;
        a32 = e32 + (size_t)erow * D + ssec * 8;
    } else {
        ahi = esin + (size_t)sgr * 512 + ssec * 8;   // lo at +256
    }

    // ---- prologue: A chunks 0,1,2 -> sets 0,1,2; W chunk 0 -> regs ----
    if (svalid) {
#pragma unroll
        for (int c = 0; c < 3; ++c) {
            if (MODE == 0) {
                const float* p = a32 + c * 32;
                pf0[c] = *(const float4*)p;
                pf1[c] = *(const float4*)(p + 4);
            } else {
                ph[c] = *(const u16x8*)(ahi + c * 32);
                pl[c] = *(const u16x8*)(ahi + 256 + c * 32);
            }
        }
    }
#pragma unroll
    for (int n = 0; n < 4; ++n) {
        size_t o = ((size_t)(wcol + n * 16 + l15)) * 32 + l4 * 8;
        bh[n] = *(const bf16x8*)(WTh + o);
        bl[n] = *(const bf16x8*)(WTl + o);
    }
    if (MODE == 0) {
        cvt_write8(pf0[0], pf1[0], &AH(0, srow, ssec * 8), &AL(0, srow, ssec * 8));
    } else {
        *(u16x8*)&AH(0, srow, ssec * 8) = ph[0];
        *(u16x8*)&AL(0, srow, ssec * 8) = pl[0];
    }
    __syncthreads();

    // ---- K loop: 8 chunks of 32; A 3-deep, W 1-deep prefetch ----
#pragma unroll
    for (int kc = 0; kc < 8; ++kc) {
        const int cur = kc & 1;
        if (kc < 5 && svalid) {            // issue A(kc+3) into set kc%3
            if (MODE == 0) {
                const float* p = a32 + (kc + 3) * 32;
                pf0[kc % 3] = *(const float4*)p;
                pf1[kc % 3] = *(const float4*)(p + 4);
            } else {
                ph[kc % 3] = *(const u16x8*)(ahi + (kc + 3) * 32);
                pl[kc % 3] = *(const u16x8*)(ahi + 256 + (kc + 3) * 32);
            }
        }
        bf16x8 ah[4], al[4];
#pragma unroll
        for (int m = 0; m < 4; ++m) {
            ah[m] = *(const bf16x8*)&AH(cur, m * 16 + l15, l4 * 8);
            al[m] = *(const bf16x8*)&AL(cur, m * 16 + l15, l4 * 8);
        }
        if (kc < 7) {                      // issue W(kc+1)
#pragma unroll
            for (int n = 0; n < 4; ++n) {
                size_t o = ((size_t)(kc + 1) * 256 + wcol + n * 16 + l15) * 32 + l4 * 8;
                bhn[n] = *(const bf16x8*)(WTh + o);
                bln[n] = *(const bf16x8*)(WTl + o);
            }
        }
#pragma unroll
        for (int m = 0; m < 4; ++m)
#pragma unroll
            for (int n = 0; n < 4; ++n) {
                acc[m][n] = __builtin_amdgcn_mfma_f32_16x16x32_bf16(
                    ah[m], bh[n], acc[m][n], 0, 0, 0);
                acc[m][n] = __builtin_amdgcn_mfma_f32_16x16x32_bf16(
                    ah[m], bl[n], acc[m][n], 0, 0, 0);
                acc[m][n] = __builtin_amdgcn_mfma_f32_16x16x32_bf16(
                    al[m], bh[n], acc[m][n], 0, 0, 0);
            }
        if (kc < 7) {                      // stage A(kc+1) from set (kc+1)%3
            const int ns = (kc + 1) % 3;
            if (MODE == 0) {
                cvt_write8(pf0[ns], pf1[ns],
                           &AH(cur ^ 1, srow, ssec * 8), &AL(cur ^ 1, srow, ssec * 8));
            } else {
                *(u16x8*)&AH(cur ^ 1, srow, ssec * 8) = ph[ns];
                *(u16x8*)&AL(cur ^ 1, srow, ssec * 8) = pl[ns];
            }
#pragma unroll
            for (int n = 0; n < 4; ++n) { bh[n] = bhn[n]; bl[n] = bln[n]; }
        }
        __syncthreads();
    }

    // ---- epilogue: bias+relu -> LDS transpose -> es row stores ----
#pragma unroll
    for (int h = 0; h < 2; ++h) {
        __syncthreads();
#pragma unroll
        for (int mm = 0; mm < 2; ++mm) {
            int m = h * 2 + mm;
#pragma unroll
            for (int n = 0; n < 4; ++n) {
                float bv = bias[wcol + n * 16 + l15];
#pragma unroll
                for (int r = 0; r < 4; ++r)
                    TR(wave, mm * 16 + l4 * 4 + r, n * 16 + l15) =
                        fmaxf(acc[m][n][r] + bv, 0.f);
            }
        }
        __syncthreads();
#pragma unroll
        for (int p = 0; p < 8; ++p) {
            int row  = p * 4 + l4;
            int grow = m0 + h * 32 + row;
            if (grow < rows) {
                float4 v = *(const float4*)&TR(wave, row, l15 * 4);
                ushort4 h4, l4v;
                split2(v.x, h4.x, l4v.x);
                split2(v.y, h4.y, l4v.y);
                split2(v.z, h4.z, l4v.z);
                split2(v.w, h4.w, l4v.w);
                size_t off = (size_t)grow * 512 + wcol + l15 * 4;
                *(ushort4*)(es + off) = h4;
                *(ushort4*)(es + off + 256) = l4v;
            }
        }
    }
#undef AH
#undef AL
#undef TR
}

// ------------------------------------------------------------------- GEMM ----
// fp32 row-full GEMM for node convs (N=10k). BN_A: scale/shift inline in
// LDS from stats_in+gamma/beta. DO_STATS: column sum/sumsq into stats_out.
template<bool BN_A, bool ADD_INIT, bool DO_STATS>
__global__ __launch_bounds__(256) void gemm_rowfull(
    const float* A, const float* __restrict__ aggr,
    const float* __restrict__ W, const float* __restrict__ bias,
    const float* __restrict__ stats_in, const float* __restrict__ gamma,
    const float* __restrict__ beta, const float* __restrict__ init,
    float* out, float* __restrict__ stats_out, int rows)
{
    __shared__ float As[16][68];
    __shared__ float Bs[16][260];
    __shared__ float ssc[256], ssf[256];

    const int tid = threadIdx.x;
    const int m0 = blockIdx.x * 64;
    const int tx = tid & 15;
    const int ty = tid >> 4;

    const int arow = tid >> 2;
    const int ak4  = (tid & 3) << 2;
    const int bk   = tid >> 4;
    const int bn4  = (tid & 15) << 2;

    if (BN_A) {
        float inv_n = 1.f / (float)rows;
        float mean = stats_in[tid] * inv_n;
        float var  = stats_in[D + tid] * inv_n - mean * mean;
        float sc = gamma[tid] * rsqrtf(var + BN_EPS);
        ssc[tid] = sc;
        ssf[tid] = beta[tid] - mean * sc;
        __syncthreads();
    }

    float acc[4][16];
#pragma unroll
    for (int i = 0; i < 4; ++i)
#pragma unroll
        for (int j = 0; j < 16; ++j) acc[i][j] = 0.f;

    for (int k0 = 0; k0 < D; k0 += 16) {
        float4 av = make_float4(0.f, 0.f, 0.f, 0.f);
        int gr = m0 + arow;
        if (gr < rows) {
            av = *(const float4*)(A + (size_t)gr * D + k0 + ak4);
            if (BN_A) {
                float4 sc = *(const float4*)&ssc[k0 + ak4];
                float4 sh = *(const float4*)&ssf[k0 + ak4];
                av.x = av.x * sc.x + sh.x;
                av.y = av.y * sc.y + sh.y;
                av.z = av.z * sc.z + sh.z;
                av.w = av.w * sc.w + sh.w;
            }
            float4 g = *(const float4*)(aggr + (size_t)gr * D + k0 + ak4);
            av.x += g.x; av.y += g.y; av.z += g.z; av.w += g.w;
        }
        As[ak4 + 0][arow] = av.x;
        As[ak4 + 1][arow] = av.y;
        As[ak4 + 2][arow] = av.z;
        As[ak4 + 3][arow] = av.w;
#pragma unroll
        for (int c = 0; c < 4; ++c)
            *(float4*)&Bs[bk][c * 64 + bn4] =
                *(const float4*)(W + (size_t)(k0 + bk) * D + c * 64 + bn4);
        __syncthreads();
#pragma unroll
        for (int k = 0; k < 16; ++k) {
            float4 a4 = *(const float4*)&As[k][ty << 2];
            float a[4] = {a4.x, a4.y, a4.z, a4.w};
#pragma unroll
            for (int jc = 0; jc < 4; ++jc) {
                float4 b4 = *(const float4*)&Bs[k][(jc << 6) + (tx << 2)];
#pragma unroll
                for (int i = 0; i < 4; ++i) {
                    acc[i][jc * 4 + 0] += a[i] * b4.x;
                    acc[i][jc * 4 + 1] += a[i] * b4.y;
                    acc[i][jc * 4 + 2] += a[i] * b4.z;
                    acc[i][jc * 4 + 3] += a[i] * b4.w;
                }
            }
        }
        __syncthreads();
    }

    float4 s4[4], q4[4];
#pragma unroll
    for (int jc = 0; jc < 4; ++jc) {
        s4[jc] = make_float4(0.f, 0.f, 0.f, 0.f);
        q4[jc] = make_float4(0.f, 0.f, 0.f, 0.f);
    }
#pragma unroll
    for (int jc = 0; jc < 4; ++jc) {
        int col = (jc << 6) + (tx << 2);
        float4 bias4 = *(const float4*)(bias + col);
#pragma unroll
        for (int i = 0; i < 4; ++i) {
            int gr = m0 + (ty << 2) + i;
            if (gr < rows) {
                float4 o;
                o.x = fmaxf(acc[i][jc * 4 + 0] + bias4.x, 0.f);
                o.y = fmaxf(acc[i][jc * 4 + 1] + bias4.y, 0.f);
                o.z = fmaxf(acc[i][jc * 4 + 2] + bias4.z, 0.f);
                o.w = fmaxf(acc[i][jc * 4 + 3] + bias4.w, 0.f);
                if (ADD_INIT) {
                    float4 iv = *(const float4*)(init + (size_t)gr * D + col);
                    o.x += iv.x; o.y += iv.y; o.z += iv.z; o.w += iv.w;
                }
                if (DO_STATS) {
                    s4[jc].x += o.x; s4[jc].y += o.y;
                    s4[jc].z += o.z; s4[jc].w += o.w;
                    q4[jc].x += o.x * o.x; q4[jc].y += o.y * o.y;
                    q4[jc].z += o.z * o.z; q4[jc].w += o.w * o.w;
                }
                *(float4*)(out + (size_t)gr * D + col) = o;
            }
        }
    }

    if (DO_STATS) {
#pragma unroll
        for (int jc = 0; jc < 4; ++jc)
            *(float4*)&Bs[ty][(jc << 6) + (tx << 2)] = s4[jc];
        __syncthreads();
        {
            float s = 0.f;
#pragma unroll
            for (int t = 0; t < 16; ++t) s += Bs[t][tid];
            atomicAdd(&stats_out[tid], s);
        }
        __syncthreads();
#pragma unroll
        for (int jc = 0; jc < 4; ++jc)
            *(float4*)&Bs[ty][(jc << 6) + (tx << 2)] = q4[jc];
        __syncthreads();
        {
            float s = 0.f;
#pragma unroll
            for (int t = 0; t < 16; ++t) s += Bs[t][tid];
            atomicAdd(&stats_out[D + tid], s);
        }
    }
}

// ----------------------------------------------------------------- launch ----
extern "C" void kernel_launch(void* const* d_in, const int* in_sizes, int n_in,
                              void* d_out, int out_size, void* d_ws, size_t ws_size,
                              hipStream_t stream)
{
    const float* node_feat = (const float*)d_in[0];
    const float* e32       = (const float*)d_in[1];
    const int*   src       = (const int*)d_in[2];
    const int*   dst       = (const int*)d_in[3];
    const float* W_conv    = (const float*)d_in[4];
    const float* b_conv    = (const float*)d_in[5];
    const float* W_edge    = (const float*)d_in[6];
    const float* b_edge    = (const float*)d_in[7];
    const float* gamma     = (const float*)d_in[8];
    const float* beta      = (const float*)d_in[9];
    float*       out       = (float*)d_out;

    const int N = in_sizes[0] / D;
    const int E = in_sizes[2];
    const int L = in_sizes[5] / D;

    float* x          = (float*)d_ws;                  // N*D f32
    float* aggr       = x + (size_t)N * D;             // N*D f32
    float* stats      = aggr + (size_t)N * D;          // L*2*D (slots)
    int*   cnt        = (int*)(stats + (size_t)L * 2 * D); // N
    int*   row_ptr    = cnt + N;                       // N+1
    int*   fillc      = row_ptr + N + 1;               // N
    int*   edge_idx   = fillc + N;                     // E
    int*   src_sorted = edge_idx + E;                  // E
    uintptr_t pa      = ((uintptr_t)(src_sorted + E) + 63) & ~(uintptr_t)63;
    ushort* WTh       = (ushort*)pa;                   // L*D*D bf16 hi
    ushort* WTl       = WTh + (size_t)L * D * D;       // L*D*D bf16 lo
    ushort* es        = WTl + (size_t)L * D * D;       // E*512 (hi|lo rows)

    int nodeBlocks    = (N + 63) / 64;
    int edgeBlocks    = (E + 63) / 64;
    int gatherBlocks  = (N + 3) / 4;
    int eThreadBlocks = (E + 255) / 256;

    // ---- one-time: zero stats slots + CSR + W_edge K-chunk-major hi/lo ----
    hipMemsetAsync(cnt, 0, (size_t)N * sizeof(int), stream);
    hipMemsetAsync(fillc, 0, (size_t)N * sizeof(int), stream);
    hipMemsetAsync(stats, 0, (size_t)L * 2 * D * sizeof(float), stream);
    hist_kernel<<<eThreadBlocks, 256, 0, stream>>>(dst, cnt, E);
    scan_kernel<<<1, 256, 0, stream>>>(cnt, row_ptr, N);
    fill_kernel<<<eThreadBlocks, 256, 0, stream>>>(
        dst, src, row_ptr, fillc, edge_idx, src_sorted, E);
    wconv_kernel<<<L * D, 256, 0, stream>>>(W_edge, WTh, WTl);

    for (int i = 0; i < L; ++i) {
        if (i == 0) {
            gather_l0<<<gatherBlocks, 256, 0, stream>>>(
                node_feat, e32, src, row_ptr, edge_idx, aggr, N);
            gemm_rowfull<false, false, true><<<nodeBlocks, 256, 0, stream>>>(
                node_feat, aggr, W_conv, b_conv, nullptr, nullptr, nullptr,
                nullptr, x, stats, N);
        } else {
            const float* st = stats + (size_t)(i - 1) * 2 * D;
            gather_sorted<<<gatherBlocks, 256, 0, stream>>>(
                x, es, src_sorted, row_ptr, st, gamma + (size_t)(i - 1) * D,
                beta + (size_t)(i - 1) * D, aggr, N);
            gemm_rowfull<true, false, true><<<nodeBlocks, 256, 0, stream>>>(
                x, aggr, W_conv + (size_t)i * D * D, b_conv + (size_t)i * D,
                st, gamma + (size_t)(i - 1) * D, beta + (size_t)(i - 1) * D,
                nullptr, x, stats + (size_t)i * 2 * D, N);
        }
        if (i == 0)
            gemm_edge_mfma<0><<<edgeBlocks, 256, 0, stream>>>(
                e32, edge_idx, nullptr, WTh, WTl, b_edge, es, E);
        else
            gemm_edge_mfma<1><<<edgeBlocks, 256, 0, stream>>>(
                nullptr, nullptr, es, WTh + (size_t)i * D * D,
                WTl + (size_t)i * D * D, b_edge + (size_t)i * D, es, E);
    }

    // final conv: layer L-1 weights on (BN_3(x), gather(es_4)), + node_feat
    {
        const float* st = stats + (size_t)(L - 1) * 2 * D;
        gather_sorted<<<gatherBlocks, 256, 0, stream>>>(
            x, es, src_sorted, row_ptr, st, gamma + (size_t)(L - 1) * D,
            beta + (size_t)(L - 1) * D, aggr, N);
        gemm_rowfull<true, true, false><<<nodeBlocks, 256, 0, stream>>>(
            x, aggr, W_conv + (size_t)(L - 1) * D * D, b_conv + (size_t)(L - 1) * D,
            st, gamma + (size_t)(L - 1) * D, beta + (size_t)(L - 1) * D,
            node_feat, out, nullptr, N);
    }
}